// Round 1
// baseline (1000.740 us; speedup 1.0000x reference)
//
#include <hip/hip_runtime.h>
#include <hip/hip_bf16.h>

// Problem constants (T,S,W,D,C,K) = (16,16,10,512,64,512)
#define T_  16
#define W_  10
#define D_  512
#define SW_ 160      // S*W
#define KD_ 1536     // 3*D  (GEMM1 reduction dim)
#define N1_ 1024     // 2*D  (GEMM1 output dim)
#define KT_ 512      // triplets per (t,w)

typedef __bf16 bf16x8 __attribute__((ext_vector_type(8)));
typedef float  f32x4  __attribute__((ext_vector_type(4)));

// async global->LDS, 16B per lane. Global address is per-lane (gather OK);
// LDS destination is wave-uniform base + lane*16 (we pass base+lane*16, same thing).
__device__ __forceinline__ void async16(const void* g, void* l) {
  __builtin_amdgcn_global_load_lds(
      (__attribute__((address_space(1))) void*)(g),
      (__attribute__((address_space(3))) void*)(l), 16, 0, 0);
}

// ---------------- K0a: cast input_data fp32 -> bf16 (same layout [16][160][512])
__global__ __launch_bounds__(256) void cast_x(const float* __restrict__ xin,
                                              __hip_bfloat16* __restrict__ xbf) {
  int i = blockIdx.x * 256 + threadIdx.x;   // grid sized exactly: 5120*256 = 1310720
  xbf[i] = __float2bfloat16(xin[i]);
}

// ---------------- K0b: W1 (1536x1024 fp32, [k][n]) -> W1t (bf16 [n][k]) tiled transpose
__global__ __launch_bounds__(256) void transpose_w1(const float* __restrict__ W1,
                                                    __hip_bfloat16* __restrict__ w1t) {
  __shared__ float tile[32 * 33];
  int k0 = blockIdx.y * 32, n0 = blockIdx.x * 32;
  int c = threadIdx.x & 31, r0 = threadIdx.x >> 5;   // 8 rows per pass
#pragma unroll
  for (int i = 0; i < 4; ++i) {
    int r = r0 + i * 8;                              // k-local
    tile[r * 33 + c] = W1[(size_t)(k0 + r) * N1_ + n0 + c];
  }
  __syncthreads();
#pragma unroll
  for (int i = 0; i < 4; ++i) {
    int r = r0 + i * 8;                              // n-local
    w1t[(size_t)(n0 + r) * KD_ + k0 + c] = __float2bfloat16(tile[c * 33 + r]);
  }
}

// ---------------- K1: gathered bf16 GEMM  relu(A@W1+b1) with column-sum epilogue.
// A row (t,w,k): concat_j x[t, tidx[t,w,j,k], :].  Output: Hsum[g][n] += col sums.
// Tile 128x128, BK=64, 4 waves (2x2 of 64x64), mfma_f32_16x16x32_bf16.
// LDS layout for both A and B tiles: [outdim row r][64 k], 128B/row, 16B blocks
// XOR-swizzled: block q stored at q^(r&7)  -> ds_read_b128 is 2-way (free).
__global__ __launch_bounds__(256) void fused_gemm1(
    const __hip_bfloat16* __restrict__ xbf,   // [16][160][512]
    const __hip_bfloat16* __restrict__ w1t,   // [1024][1536]
    const int* __restrict__ tidx,             // [16][10][3][512]
    const float* __restrict__ b1,             // [1024]
    float* __restrict__ Hsum)                 // [160][1024]
{
  __shared__ __align__(16) char Abuf[16384];
  __shared__ __align__(16) char Bbuf[16384];
  __shared__ int   idx_s[384];
  __shared__ float red[128];

  const int tid = threadIdx.x;
  const int bx  = blockIdx.x;
  const int nt  = bx & 7;
  const int mt  = (bx >> 3) & 3;
  const int g   = bx >> 5;            // 0..159  == t*10+w
  const int t   = g / W_;
  const int n0  = nt << 7;
  const int m0  = mt << 7;

  for (int i = tid; i < 384; i += 256) {
    int j = i >> 7, r = i & 127;
    idx_s[i] = tidx[((g * 3 + j) << 9) + m0 + r];
  }
  __syncthreads();

  const int ln    = tid & 63;
  const int wv    = tid >> 6;
  const int cb    = ((ln & 7) ^ (ln >> 3)) << 3;  // swizzled column offset (elems)
  const int wr    = wv >> 1, wc = wv & 1;
  const int col16 = ln & 15, quad = ln >> 4;

  const __hip_bfloat16* xt = xbf + (size_t)t * (SW_ * D_);

  int aoff[3][4], boff[4], ldsoff[4];
#pragma unroll
  for (int s = 0; s < 4; ++s) {
    int r = (wv << 5) + (s << 3) + (ln >> 3);       // staging row 0..127
#pragma unroll
    for (int j = 0; j < 3; ++j)
      aoff[j][s] = idx_s[(j << 7) + r] * D_ + cb;
    boff[s]   = (n0 + r) * KD_ + cb;
    ldsoff[s] = ((wv * 4 + s) << 10) + (ln << 4);
  }

  f32x4 acc[4][4];
#pragma unroll
  for (int a = 0; a < 4; ++a)
#pragma unroll
    for (int b = 0; b < 4; ++b)
      acc[a][b] = (f32x4){0.f, 0.f, 0.f, 0.f};

#pragma unroll 1
  for (int kk = 0; kk < KD_; kk += 64) {
    const int j  = kk >> 9;        // which of the 3 gathered segments
    const int c0 = kk & 511;       // column within segment
    __syncthreads();               // protect LDS from overwrite
#pragma unroll
    for (int s = 0; s < 4; ++s) {
      async16(xt + aoff[j][s] + c0, Abuf + ldsoff[s]);
      async16(w1t + boff[s] + kk,   Bbuf + ldsoff[s]);
    }
    __syncthreads();               // drains vmcnt, then barrier

#pragma unroll
    for (int ks = 0; ks < 2; ++ks) {
      bf16x8 af[4], bfr[4];
#pragma unroll
      for (int a = 0; a < 4; ++a) {
        int q  = (ks << 2) + quad;
        int rm = (wr << 6) + (a << 4) + col16;
        af[a]  = *(const bf16x8*)(Abuf + (rm << 7) + ((q ^ (rm & 7)) << 4));
        int rn = (wc << 6) + (a << 4) + col16;
        bfr[a] = *(const bf16x8*)(Bbuf + (rn << 7) + ((q ^ (rn & 7)) << 4));
      }
#pragma unroll
      for (int a = 0; a < 4; ++a)
#pragma unroll
        for (int b = 0; b < 4; ++b)
          acc[a][b] = __builtin_amdgcn_mfma_f32_16x16x32_bf16(af[a], bfr[b], acc[a][b], 0, 0, 0);
    }
  }

  // Epilogue: +b1, relu, sum over the 128 tile rows, accumulate into Hsum.
  __syncthreads();
  if (tid < 128) red[tid] = 0.f;
  __syncthreads();
#pragma unroll
  for (int b = 0; b < 4; ++b) {
    int   nl   = (wc << 6) + (b << 4) + col16;   // column within 128-tile
    float bias = b1[n0 + nl];
    float v    = 0.f;
#pragma unroll
    for (int a = 0; a < 4; ++a)
#pragma unroll
      for (int r5 = 0; r5 < 4; ++r5)
        v += fmaxf(acc[a][b][r5] + bias, 0.f);   // rows quad*4+r5 + a*16 (+wr*64)
    v += __shfl_xor(v, 16);                       // sum across quads
    v += __shfl_xor(v, 32);
    if (quad == 0) atomicAdd(&red[nl], v);        // combine wr=0 / wr=1 waves
  }
  __syncthreads();
  if (tid < 128) atomicAdd(&Hsum[(size_t)g * N1_ + n0 + tid], red[tid]);
}

// ---------------- K2: small fp32 GEMM  out[M,N] = opt_relu(A[M,Kd]@B[Kd,N] + bscale*bias)
// grid (N/64, M/16); block 256 = 4 waves; wave w computes rows m0+w*4..+3 (A broadcast from LDS).
__global__ __launch_bounds__(256) void small_gemm(
    const float* __restrict__ A, int Kd,
    const float* __restrict__ B, int N,
    const float* __restrict__ bias, float bscale, int do_relu,
    float* __restrict__ out)
{
  __shared__ float As[16 * 64];
  const int tid = threadIdx.x;
  const int n0 = blockIdx.x * 64, m0 = blockIdx.y * 16;
  const int nl = tid & 63, wv = tid >> 6;
  float acc[4] = {0.f, 0.f, 0.f, 0.f};

  for (int kk = 0; kk < Kd; kk += 64) {
    __syncthreads();
    for (int f = tid; f < 1024; f += 256) {
      int m = f >> 6, k = f & 63;
      As[f] = A[(size_t)(m0 + m) * Kd + kk + k];
    }
    __syncthreads();
#pragma unroll 8
    for (int k = 0; k < 64; ++k) {
      float bv = B[(size_t)(kk + k) * N + n0 + nl];
#pragma unroll
      for (int i = 0; i < 4; ++i)
        acc[i] += As[(wv * 4 + i) * 64 + k] * bv;
    }
  }
  float bb = bias[n0 + nl] * bscale;
#pragma unroll
  for (int i = 0; i < 4; ++i) {
    float v = acc[i] + bb;
    if (do_relu) v = fmaxf(v, 0.f);
    out[(size_t)(m0 + wv * 4 + i) * N + n0 + nl] = v;
  }
}

// ---------------- K3: score = o@Wc + bc, softmax over 64. One block per (t,w) row.
__global__ __launch_bounds__(256) void head_kernel(
    const float* __restrict__ o,    // [160][512]
    const float* __restrict__ Wc,   // [512][64]
    const float* __restrict__ bc,   // [64]
    float* __restrict__ out)        // [160][64]
{
  __shared__ float os[512];
  __shared__ float scr[256];
  const int row = blockIdx.x, tid = threadIdx.x;
  for (int i = tid; i < 512; i += 256) os[i] = o[(size_t)row * 512 + i];
  __syncthreads();
  const int n = tid & 63, q = tid >> 6;
  float p = 0.f;
  for (int k = q * 128; k < q * 128 + 128; ++k) p += os[k] * Wc[k * 64 + n];
  scr[tid] = p;
  __syncthreads();
  if (tid < 64) {
    float s = scr[n] + scr[64 + n] + scr[128 + n] + scr[192 + n] + bc[n];
    float m = s;
#pragma unroll
    for (int off = 32; off; off >>= 1) m = fmaxf(m, __shfl_xor(m, off));
    float e = expf(s - m);
    float sum = e;
#pragma unroll
    for (int off = 32; off; off >>= 1) sum += __shfl_xor(sum, off);
    out[(size_t)row * 64 + n] = e / sum;
  }
}

extern "C" void kernel_launch(void* const* d_in, const int* in_sizes, int n_in,
                              void* d_out, int out_size, void* d_ws, size_t ws_size,
                              hipStream_t stream) {
  const float* x_in = (const float*)d_in[0];
  const int*   tidx = (const int*)d_in[1];
  const float* W1 = (const float*)d_in[2];
  const float* b1 = (const float*)d_in[3];
  const float* W2 = (const float*)d_in[4];
  const float* b2 = (const float*)d_in[5];
  const float* W3 = (const float*)d_in[6];
  const float* b3 = (const float*)d_in[7];
  const float* W4 = (const float*)d_in[8];
  const float* b4 = (const float*)d_in[9];
  const float* Wc = (const float*)d_in[10];
  const float* bc = (const float*)d_in[11];
  float* out = (float*)d_out;
  (void)in_sizes; (void)n_in; (void)out_size; (void)ws_size;

  // workspace layout (bytes)
  char* ws = (char*)d_ws;
  __hip_bfloat16* xbf = (__hip_bfloat16*)(ws + 0);        // 16*160*512 bf16 = 2,621,440
  __hip_bfloat16* w1t = (__hip_bfloat16*)(ws + 2621440);  // 1024*1536 bf16 = 3,145,728
  float* Hs   = (float*)(ws + 5767168);                   // 160*1024 f32 = 655,360
  float* gbuf = (float*)(ws + 6422528);                   // 160*512  f32 = 327,680
  float* ubuf = (float*)(ws + 6750208);                   // 160*1024 f32 = 655,360
  float* obuf = (float*)(ws + 7405568);                   // 160*512  f32 = 327,680

  cast_x<<<5120, 256, 0, stream>>>(x_in, xbf);
  transpose_w1<<<dim3(32, 48), 256, 0, stream>>>(W1, w1t);
  hipMemsetAsync(Hs, 0, 160 * 1024 * sizeof(float), stream);

  // Hsum[g][n] = sum_k relu(trip[g,k,:]@W1 + b1)[n]   (258 GFLOP, bf16 MFMA)
  fused_gemm1<<<5120, 256, 0, stream>>>(xbf, w1t, tidx, b1, Hs);

  // g = Hsum@W2 + K*b2   (sum over K commutes with linear W2)
  small_gemm<<<dim3(8, 10), 256, 0, stream>>>(Hs, 1024, W2, 512, b2, (float)KT_, 0, gbuf);
  // u = relu(g@W3 + b3)
  small_gemm<<<dim3(16, 10), 256, 0, stream>>>(gbuf, 512, W3, 1024, b3, 1.f, 1, ubuf);
  // o = u@W4 + b4
  small_gemm<<<dim3(8, 10), 256, 0, stream>>>(ubuf, 1024, W4, 512, b4, 1.f, 0, obuf);
  // softmax(o@Wc + bc)
  head_kernel<<<160, 256, 0, stream>>>(obuf, Wc, bc, out);
}

// Round 2
// 445.463 us; speedup vs baseline: 2.2465x; 2.2465x over previous
//
#include <hip/hip_runtime.h>
#include <hip/hip_bf16.h>

// Problem constants (T,S,W,D,C,K) = (16,16,10,512,64,512)
#define T_  16
#define W_  10
#define D_  512
#define SW_ 160      // S*W
#define KD_ 1536     // 3*D  (GEMM1 reduction dim)
#define N1_ 1024     // 2*D  (GEMM1 output dim)
#define KT_ 512      // triplets per (t,w)

typedef __bf16 bf16x8 __attribute__((ext_vector_type(8)));
typedef float  f32x4  __attribute__((ext_vector_type(4)));

// async global->LDS, 16B per lane. Global address is per-lane (gather OK);
// LDS destination is wave-uniform base + lane*16 (we pass base+lane*16, same thing).
__device__ __forceinline__ void async16(const void* g, void* l) {
  __builtin_amdgcn_global_load_lds(
      (__attribute__((address_space(1))) void*)(g),
      (__attribute__((address_space(3))) void*)(l), 16, 0, 0);
}

// ---------------- K0a: cast input_data fp32 -> bf16 (same layout [16][160][512])
__global__ __launch_bounds__(256) void cast_x(const float* __restrict__ xin,
                                              __hip_bfloat16* __restrict__ xbf) {
  int i = blockIdx.x * 256 + threadIdx.x;   // grid sized exactly: 5120*256 = 1310720
  xbf[i] = __float2bfloat16(xin[i]);
}

// ---------------- K0b: W1 (1536x1024 fp32, [k][n]) -> W1t (bf16 [n][k]) tiled transpose
__global__ __launch_bounds__(256) void transpose_w1(const float* __restrict__ W1,
                                                    __hip_bfloat16* __restrict__ w1t) {
  __shared__ float tile[32 * 33];
  int k0 = blockIdx.y * 32, n0 = blockIdx.x * 32;
  int c = threadIdx.x & 31, r0 = threadIdx.x >> 5;   // 8 rows per pass
#pragma unroll
  for (int i = 0; i < 4; ++i) {
    int r = r0 + i * 8;                              // k-local
    tile[r * 33 + c] = W1[(size_t)(k0 + r) * N1_ + n0 + c];
  }
  __syncthreads();
#pragma unroll
  for (int i = 0; i < 4; ++i) {
    int r = r0 + i * 8;                              // n-local
    w1t[(size_t)(n0 + r) * KD_ + k0 + c] = __float2bfloat16(tile[c * 33 + r]);
  }
}

// ---------------- K1: gathered bf16 GEMM  relu(A@W1+b1) with column-sum epilogue.
// A row (t,w,k): concat_j x[t, tidx[t,w,j,k], :].  Output: Hsum[g][n] += col sums.
// Tile 128x128, BK=64, 4 waves (2x2 of 64x64), mfma_f32_16x16x32_bf16.
// LDS layout for both A and B tiles: [outdim row r][64 k], 128B/row, 16B blocks
// XOR-swizzled: block q stored at q^(r&7)  -> ds_read_b128 is 2-way (free).
__global__ __launch_bounds__(256) void fused_gemm1(
    const __hip_bfloat16* __restrict__ xbf,   // [16][160][512]
    const __hip_bfloat16* __restrict__ w1t,   // [1024][1536]
    const int* __restrict__ tidx,             // [16][10][3][512]
    const float* __restrict__ b1,             // [1024]
    float* __restrict__ Hsum)                 // [160][1024]
{
  __shared__ __align__(16) char Abuf[16384];
  __shared__ __align__(16) char Bbuf[16384];
  __shared__ int   idx_s[384];
  __shared__ float red[128];

  const int tid = threadIdx.x;
  const int bx  = blockIdx.x;
  const int nt  = bx & 7;
  const int mt  = (bx >> 3) & 3;
  const int g   = bx >> 5;            // 0..159  == t*10+w
  const int t   = g / W_;
  const int n0  = nt << 7;
  const int m0  = mt << 7;

  for (int i = tid; i < 384; i += 256) {
    int j = i >> 7, r = i & 127;
    idx_s[i] = tidx[((g * 3 + j) << 9) + m0 + r];
  }
  __syncthreads();

  const int ln    = tid & 63;
  const int wv    = tid >> 6;
  const int cb    = ((ln & 7) ^ (ln >> 3)) << 3;  // swizzled column offset (elems)
  const int wr    = wv >> 1, wc = wv & 1;
  const int col16 = ln & 15, quad = ln >> 4;

  const __hip_bfloat16* xt = xbf + (size_t)t * (SW_ * D_);

  int aoff[3][4], boff[4], ldsoff[4];
#pragma unroll
  for (int s = 0; s < 4; ++s) {
    int r = (wv << 5) + (s << 3) + (ln >> 3);       // staging row 0..127
#pragma unroll
    for (int j = 0; j < 3; ++j)
      aoff[j][s] = idx_s[(j << 7) + r] * D_ + cb;
    boff[s]   = (n0 + r) * KD_ + cb;
    ldsoff[s] = ((wv * 4 + s) << 10) + (ln << 4);
  }

  f32x4 acc[4][4];
#pragma unroll
  for (int a = 0; a < 4; ++a)
#pragma unroll
    for (int b = 0; b < 4; ++b)
      acc[a][b] = (f32x4){0.f, 0.f, 0.f, 0.f};

#pragma unroll 1
  for (int kk = 0; kk < KD_; kk += 64) {
    const int j  = kk >> 9;        // which of the 3 gathered segments
    const int c0 = kk & 511;       // column within segment
    __syncthreads();               // protect LDS from overwrite
#pragma unroll
    for (int s = 0; s < 4; ++s) {
      async16(xt + aoff[j][s] + c0, Abuf + ldsoff[s]);
      async16(w1t + boff[s] + kk,   Bbuf + ldsoff[s]);
    }
    __syncthreads();               // drains vmcnt, then barrier

#pragma unroll
    for (int ks = 0; ks < 2; ++ks) {
      bf16x8 af[4], bfr[4];
#pragma unroll
      for (int a = 0; a < 4; ++a) {
        int q  = (ks << 2) + quad;
        int rm = (wr << 6) + (a << 4) + col16;
        af[a]  = *(const bf16x8*)(Abuf + (rm << 7) + ((q ^ (rm & 7)) << 4));
        int rn = (wc << 6) + (a << 4) + col16;
        bfr[a] = *(const bf16x8*)(Bbuf + (rn << 7) + ((q ^ (rn & 7)) << 4));
      }
#pragma unroll
      for (int a = 0; a < 4; ++a)
#pragma unroll
        for (int b = 0; b < 4; ++b)
          acc[a][b] = __builtin_amdgcn_mfma_f32_16x16x32_bf16(af[a], bfr[b], acc[a][b], 0, 0, 0);
    }
  }

  // Epilogue: +b1, relu, sum over the 128 tile rows, accumulate into Hsum.
  __syncthreads();
  if (tid < 128) red[tid] = 0.f;
  __syncthreads();
#pragma unroll
  for (int b = 0; b < 4; ++b) {
    int   nl   = (wc << 6) + (b << 4) + col16;   // column within 128-tile
    float bias = b1[n0 + nl];
    float v    = 0.f;
#pragma unroll
    for (int a = 0; a < 4; ++a)
#pragma unroll
      for (int r5 = 0; r5 < 4; ++r5)
        v += fmaxf(acc[a][b][r5] + bias, 0.f);   // rows quad*4+r5 + a*16 (+wr*64)
    v += __shfl_xor(v, 16);                       // sum across quads
    v += __shfl_xor(v, 32);
    if (quad == 0) atomicAdd(&red[nl], v);        // combine wr=0 / wr=1 waves
  }
  __syncthreads();
  if (tid < 128) atomicAdd(&Hsum[(size_t)g * N1_ + n0 + tid], red[tid]);
}

// ---------------- K2: fused tail. One block (512 thr) per row g.
// g = Hs[g]@W2 + K*b2 ; u = relu(g@W3+b3) ; o = u@W4+b4 ; out = softmax(o@Wc+bc).
// Weights are L2-resident (~6 MB). Each dot batches 16 independent global
// loads into registers before the FMA pass -> 16 loads in flight per thread.
__global__ __launch_bounds__(512) void tail_kernel(
    const float* __restrict__ Hs,   // [160][1024]
    const float* __restrict__ W2,   // [1024][512]
    const float* __restrict__ b2,   // [512]
    const float* __restrict__ W3,   // [512][1024]
    const float* __restrict__ b3,   // [1024]
    const float* __restrict__ W4,   // [1024][512]
    const float* __restrict__ b4,   // [512]
    const float* __restrict__ Wc,   // [512][64]
    const float* __restrict__ bc,   // [64]
    float* __restrict__ out)        // [160][64]
{
  __shared__ float bufA[1024];   // hs, later u
  __shared__ float bufB[512];    // g, later o
  __shared__ float scr[512];
  const int g = blockIdx.x, tid = threadIdx.x;

  bufA[tid]       = Hs[(size_t)g * 1024 + tid];
  bufA[tid + 512] = Hs[(size_t)g * 1024 + 512 + tid];
  __syncthreads();

  // ---- g[n] = sum_k hs[k]*W2[k][n] + KT_*b2[n]   (n = tid, k = 1024)
  {
    float acc = 0.f;
    for (int k0 = 0; k0 < 1024; k0 += 16) {
      float w[16];
#pragma unroll
      for (int i = 0; i < 16; ++i) w[i] = W2[(size_t)(k0 + i) * 512 + tid];
#pragma unroll
      for (int i = 0; i < 16; ++i) acc += bufA[k0 + i] * w[i];
    }
    bufB[tid] = acc + (float)KT_ * b2[tid];
  }
  __syncthreads();   // bufB ready; all reads of bufA done

  // ---- u[n] = relu(sum_k g[k]*W3[k][n] + b3[n])   (1024 outputs, 2 per thread)
  {
    float r0acc[2];
#pragma unroll
    for (int rep = 0; rep < 2; ++rep) {
      int n = tid + rep * 512;
      float acc = 0.f;
      for (int k0 = 0; k0 < 512; k0 += 16) {
        float w[16];
#pragma unroll
        for (int i = 0; i < 16; ++i) w[i] = W3[(size_t)(k0 + i) * 1024 + n];
#pragma unroll
        for (int i = 0; i < 16; ++i) acc += bufB[k0 + i] * w[i];
      }
      r0acc[rep] = fmaxf(acc + b3[n], 0.f);
    }
    bufA[tid]       = r0acc[0];   // overwrite hs (all stage-1 reads completed)
    bufA[tid + 512] = r0acc[1];
  }
  __syncthreads();   // u ready; all reads of bufB done

  // ---- o[n] = sum_k u[k]*W4[k][n] + b4[n]   (n = tid, k = 1024)
  {
    float acc = 0.f;
    for (int k0 = 0; k0 < 1024; k0 += 16) {
      float w[16];
#pragma unroll
      for (int i = 0; i < 16; ++i) w[i] = W4[(size_t)(k0 + i) * 512 + tid];
#pragma unroll
      for (int i = 0; i < 16; ++i) acc += bufA[k0 + i] * w[i];
    }
    bufB[tid] = acc + b4[tid];
  }
  __syncthreads();   // o ready

  // ---- score[n] = sum_k o[k]*Wc[k][n] + bc[n]; softmax over n=64
  {
    const int n = tid & 63, q = tid >> 6;       // 8 waves cover k in 64-chunks
    float p = 0.f;
#pragma unroll
    for (int k0 = 0; k0 < 64; k0 += 16) {
      float w[16];
#pragma unroll
      for (int i = 0; i < 16; ++i) w[i] = Wc[(size_t)(q * 64 + k0 + i) * 64 + n];
#pragma unroll
      for (int i = 0; i < 16; ++i) p += bufB[q * 64 + k0 + i] * w[i];
    }
    scr[tid] = p;
  }
  __syncthreads();
  if (tid < 64) {
    float s = bc[tid];
#pragma unroll
    for (int q = 0; q < 8; ++q) s += scr[q * 64 + tid];
    float m = s;
#pragma unroll
    for (int off = 32; off; off >>= 1) m = fmaxf(m, __shfl_xor(m, off));
    float e = expf(s - m);
    float sum = e;
#pragma unroll
    for (int off = 32; off; off >>= 1) sum += __shfl_xor(sum, off);
    out[(size_t)g * 64 + tid] = e / sum;
  }
}

extern "C" void kernel_launch(void* const* d_in, const int* in_sizes, int n_in,
                              void* d_out, int out_size, void* d_ws, size_t ws_size,
                              hipStream_t stream) {
  const float* x_in = (const float*)d_in[0];
  const int*   tidx = (const int*)d_in[1];
  const float* W1 = (const float*)d_in[2];
  const float* b1 = (const float*)d_in[3];
  const float* W2 = (const float*)d_in[4];
  const float* b2 = (const float*)d_in[5];
  const float* W3 = (const float*)d_in[6];
  const float* b3 = (const float*)d_in[7];
  const float* W4 = (const float*)d_in[8];
  const float* b4 = (const float*)d_in[9];
  const float* Wc = (const float*)d_in[10];
  const float* bc = (const float*)d_in[11];
  float* out = (float*)d_out;
  (void)in_sizes; (void)n_in; (void)out_size; (void)ws_size;

  // workspace layout (bytes)
  char* ws = (char*)d_ws;
  __hip_bfloat16* xbf = (__hip_bfloat16*)(ws + 0);        // 16*160*512 bf16 = 2,621,440
  __hip_bfloat16* w1t = (__hip_bfloat16*)(ws + 2621440);  // 1024*1536 bf16 = 3,145,728
  float* Hs   = (float*)(ws + 5767168);                   // 160*1024 f32 = 655,360

  cast_x<<<5120, 256, 0, stream>>>(x_in, xbf);
  transpose_w1<<<dim3(32, 48), 256, 0, stream>>>(W1, w1t);
  hipMemsetAsync(Hs, 0, 160 * 1024 * sizeof(float), stream);

  // Hsum[g][n] = sum_k relu(trip[g,k,:]@W1 + b1)[n]   (258 GFLOP, bf16 MFMA)
  fused_gemm1<<<5120, 256, 0, stream>>>(xbf, w1t, tidx, b1, Hs);

  // fused tail: g -> u -> o -> softmax, one block per row
  tail_kernel<<<160, 512, 0, stream>>>(Hs, W2, b2, W3, b3, W4, b4, Wc, bc, out);
}

// Round 3
// 208.203 us; speedup vs baseline: 4.8066x; 2.1396x over previous
//
#include <hip/hip_runtime.h>
#include <hip/hip_bf16.h>

// Problem constants (T,S,W,D,C,K) = (16,16,10,512,64,512)
#define T_  16
#define W_  10
#define D_  512
#define SW_ 160      // S*W
#define N1_ 1024     // 2*D
#define KT_ 512      // triplets per (t,w)

typedef __bf16 bf16x8 __attribute__((ext_vector_type(8)));
typedef float  f32x4  __attribute__((ext_vector_type(4)));

// async global->LDS, 16B per lane (global addr per-lane; LDS dest = wave base + lane*16)
__device__ __forceinline__ void async16(const void* g, void* l) {
  __builtin_amdgcn_global_load_lds(
      (__attribute__((address_space(1))) void*)(g),
      (__attribute__((address_space(3))) void*)(l), 16, 0, 0);
}

__device__ __forceinline__ float lo16(unsigned v) { return __uint_as_float(v << 16); }
__device__ __forceinline__ float hi16(unsigned v) { return __uint_as_float(v & 0xffff0000u); }

// ---------------- K0a: cast input_data fp32 -> bf16 ([16][160][512])
__global__ __launch_bounds__(256) void cast_x(const float* __restrict__ xin,
                                              __hip_bfloat16* __restrict__ xbf) {
  int i = blockIdx.x * 256 + threadIdx.x;   // 5120*256 = 1310720 exact
  xbf[i] = __float2bfloat16(xin[i]);
}

// ---------------- K0b: W1 (1536x1024 fp32 [k][n]) -> w1t (bf16 [n][1536])
__global__ __launch_bounds__(256) void transpose_w1(const float* __restrict__ W1,
                                                    __hip_bfloat16* __restrict__ w1t) {
  __shared__ float tile[32 * 33];
  int k0 = blockIdx.y * 32, n0 = blockIdx.x * 32;
  int c = threadIdx.x & 31, r0 = threadIdx.x >> 5;
#pragma unroll
  for (int i = 0; i < 4; ++i) {
    int r = r0 + i * 8;
    tile[r * 33 + c] = W1[(size_t)(k0 + r) * N1_ + n0 + c];
  }
  __syncthreads();
#pragma unroll
  for (int i = 0; i < 4; ++i) {
    int r = r0 + i * 8;
    w1t[(size_t)(n0 + r) * 1536 + k0 + c] = __float2bfloat16(tile[c * 33 + r]);
  }
}

// ---------------- K1: fused P-tile GEMM + gather/relu/reduce.
// Block = (t, 32-col window n0). Phase 1: P[j][sw][nc] = sum_k x[t,sw,k]*W1[j*512+k][n0+nc]
// via bf16 MFMA (C = [160 x 96], K=512), result stored bf16 in LDS (stride 72 B).
// Phase 2: for w, k: Hsum[t*10+w][n0+nc] += relu(P0[i0]+P1[i1]+P2[i2]+b1).
__global__ __launch_bounds__(256) void group_kernel(
    const __hip_bfloat16* __restrict__ xbf,   // [16][160][512]
    const __hip_bfloat16* __restrict__ w1t,   // [1024][1536]
    const int* __restrict__ tidx,             // [16][10][3][512]
    const float* __restrict__ b1,             // [1024]
    float* __restrict__ Hsum)                 // [160][1024]
{
  __shared__ __align__(16) char smem[43008];
  char* Abuf  = smem;                      // [0, 20480)   phase 1
  char* Bbuf  = smem + 20480;              // [20480, 32768) phase 1
  char* Ptile = smem;                      // [0, 34560)   phase 2 (overlaps staging)
  int*  idx_s = (int*)(smem + 34560);      // 1536 ints = 6144 B
  float* red  = (float*)(smem + 40704);    // 4 waves x 32 cols = 512 B

  const int tid = threadIdx.x;
  const int bx  = blockIdx.x;
  const int t   = bx >> 5;
  const int nt  = bx & 31;
  const int n0  = nt << 5;                 // 32-col output window

  const int ln = tid & 63, wv = tid >> 6;
  const int wr = wv >> 1, wc = wv & 1;     // 2x2 wave grid: 80 rows x 48 cols each
  const int col16 = ln & 15, quad = ln >> 4;

  const __hip_bfloat16* xt = xbf + (size_t)t * (SW_ * D_);

  // staging offsets (elements) — swizzle: chunk q stored at q^(r&7)
  int aoff[5], lofA[5];
#pragma unroll
  for (int s = 0; s < 5; ++s) {            // A: 160 rows x 8 chunks = 1280
    int i = s * 256 + tid, r = i >> 3, q = i & 7;
    aoff[s] = r * 512 + ((q ^ (r & 7)) << 3);
    lofA[s] = i << 4;
  }
  int boff[3], lofB[3];
#pragma unroll
  for (int s = 0; s < 3; ++s) {            // B: 96 rows (j*32+nc) x 8 chunks = 768
    int i = s * 256 + tid, r = i >> 3, q = i & 7;
    int nc = r & 31, j = r >> 5;
    boff[s] = (n0 + nc) * 1536 + j * 512 + ((q ^ (r & 7)) << 3);
    lofB[s] = i << 4;
  }

  f32x4 acc[5][3];
#pragma unroll
  for (int a = 0; a < 5; ++a)
#pragma unroll
    for (int b = 0; b < 3; ++b)
      acc[a][b] = (f32x4){0.f, 0.f, 0.f, 0.f};

  // ---- phase 1: K-loop
#pragma unroll 1
  for (int kk = 0; kk < 512; kk += 64) {
    __syncthreads();
#pragma unroll
    for (int s = 0; s < 5; ++s) async16(xt + aoff[s] + kk, Abuf + lofA[s]);
#pragma unroll
    for (int s = 0; s < 3; ++s) async16(w1t + boff[s] + kk, Bbuf + lofB[s]);
    __syncthreads();

#pragma unroll
    for (int ks = 0; ks < 2; ++ks) {
      const int qq = (ks << 2) + quad;
      bf16x8 af[5], bfr[3];
#pragma unroll
      for (int a = 0; a < 5; ++a) {
        int rm = wr * 80 + a * 16 + col16;
        af[a] = *(const bf16x8*)(Abuf + rm * 128 + ((qq ^ (rm & 7)) << 4));
      }
#pragma unroll
      for (int b = 0; b < 3; ++b) {
        int rn = wc * 48 + b * 16 + col16;
        bfr[b] = *(const bf16x8*)(Bbuf + rn * 128 + ((qq ^ (rn & 7)) << 4));
      }
#pragma unroll
      for (int a = 0; a < 5; ++a)
#pragma unroll
        for (int b = 0; b < 3; ++b)
          acc[a][b] = __builtin_amdgcn_mfma_f32_16x16x32_bf16(af[a], bfr[b], acc[a][b], 0, 0, 0);
    }
  }

  __syncthreads();   // all staging reads done; smem now becomes Ptile

  // ---- write P to LDS as bf16, layout [j][sw][nc], row stride 72 B
#pragma unroll
  for (int a = 0; a < 5; ++a)
#pragma unroll
    for (int b = 0; b < 3; ++b) {
      int c = wc * 48 + b * 16 + col16;     // 0..95
      int j = c >> 5, nc = c & 31;
      int mb = wr * 80 + a * 16 + quad * 4;
#pragma unroll
      for (int r = 0; r < 4; ++r)
        *(__hip_bfloat16*)(Ptile + (j * 160 + mb + r) * 72 + nc * 2) =
            __float2bfloat16(acc[a][b][r]);
    }

  // ---- phase 2: gather + relu + reduce over k, per w
  const int nq = tid & 7;                   // 4 cols: nc = nq*4..+3
  const int kq = tid >> 3;                  // 0..31, k in [kq*16, kq*16+16)
  const float4 bias4 = *(const float4*)(b1 + n0 + (nq << 2));

#pragma unroll 1
  for (int w = 0; w < 10; ++w) {
    __syncthreads();                        // Ptile writes done / prev-w idx reads done
    {
      const int* src = tidx + (size_t)(t * 10 + w) * 1536;
      async16(src + (tid << 2), (char*)idx_s + (tid << 4));
      if (tid < 128) async16(src + 1024 + (tid << 2), (char*)idx_s + 4096 + (tid << 4));
    }
    __syncthreads();                        // idx ready (barrier drains vmcnt)

    f32x4 a4 = (f32x4){0.f, 0.f, 0.f, 0.f};
#pragma unroll
    for (int u = 0; u < 4; ++u) {
      const int kb = (kq << 4) + (u << 2);
      int4 i0 = *(const int4*)(idx_s + kb);
      int4 i1 = *(const int4*)(idx_s + 512 + kb);
      int4 i2 = *(const int4*)(idx_s + 1024 + kb);
#define STEP(IA, IB, IC)                                                          \
      {                                                                           \
        uint2 p0 = *(const uint2*)(Ptile + (IA) * 72 + (nq << 3));                \
        uint2 p1 = *(const uint2*)(Ptile + 11520 + (IB) * 72 + (nq << 3));        \
        uint2 p2 = *(const uint2*)(Ptile + 23040 + (IC) * 72 + (nq << 3));        \
        a4.x += fmaxf(lo16(p0.x) + lo16(p1.x) + lo16(p2.x) + bias4.x, 0.f);       \
        a4.y += fmaxf(hi16(p0.x) + hi16(p1.x) + hi16(p2.x) + bias4.y, 0.f);       \
        a4.z += fmaxf(lo16(p0.y) + lo16(p1.y) + lo16(p2.y) + bias4.z, 0.f);       \
        a4.w += fmaxf(hi16(p0.y) + hi16(p1.y) + hi16(p2.y) + bias4.w, 0.f);       \
      }
      STEP(i0.x, i1.x, i2.x)
      STEP(i0.y, i1.y, i2.y)
      STEP(i0.z, i1.z, i2.z)
      STEP(i0.w, i1.w, i2.w)
#undef STEP
    }

    // reduce over kq (lane bits 3..5), then across waves via LDS
#pragma unroll
    for (int off = 8; off <= 32; off <<= 1) {
      a4.x += __shfl_xor(a4.x, off);
      a4.y += __shfl_xor(a4.y, off);
      a4.z += __shfl_xor(a4.z, off);
      a4.w += __shfl_xor(a4.w, off);
    }
    if ((ln >> 3) == 0)
      *(f32x4*)(red + wv * 32 + (nq << 2)) = a4;
    __syncthreads();
    if (tid < 32) {
      float s = red[tid] + red[32 + tid] + red[64 + tid] + red[96 + tid];
      Hsum[(size_t)(t * 10 + w) * N1_ + n0 + tid] = s;
    }
  }
}

// ---------------- K2: fused tail. One block (512 thr) per row g.
__global__ __launch_bounds__(512) void tail_kernel(
    const float* __restrict__ Hs,   // [160][1024]
    const float* __restrict__ W2,   // [1024][512]
    const float* __restrict__ b2,   // [512]
    const float* __restrict__ W3,   // [512][1024]
    const float* __restrict__ b3,   // [1024]
    const float* __restrict__ W4,   // [1024][512]
    const float* __restrict__ b4,   // [512]
    const float* __restrict__ Wc,   // [512][64]
    const float* __restrict__ bc,   // [64]
    float* __restrict__ out)        // [160][64]
{
  __shared__ float bufA[1024];   // hs, later u
  __shared__ float bufB[512];    // g, later o
  __shared__ float scr[512];
  const int g = blockIdx.x, tid = threadIdx.x;

  bufA[tid]       = Hs[(size_t)g * 1024 + tid];
  bufA[tid + 512] = Hs[(size_t)g * 1024 + 512 + tid];
  __syncthreads();

  {  // g[n] = hs@W2 + KT_*b2
    float acc = 0.f;
    for (int k0 = 0; k0 < 1024; k0 += 16) {
      float w[16];
#pragma unroll
      for (int i = 0; i < 16; ++i) w[i] = W2[(size_t)(k0 + i) * 512 + tid];
#pragma unroll
      for (int i = 0; i < 16; ++i) acc += bufA[k0 + i] * w[i];
    }
    bufB[tid] = acc + (float)KT_ * b2[tid];
  }
  __syncthreads();

  {  // u = relu(g@W3 + b3), 2 outputs/thread
    float r0acc[2];
#pragma unroll
    for (int rep = 0; rep < 2; ++rep) {
      int n = tid + rep * 512;
      float acc = 0.f;
      for (int k0 = 0; k0 < 512; k0 += 16) {
        float w[16];
#pragma unroll
        for (int i = 0; i < 16; ++i) w[i] = W3[(size_t)(k0 + i) * 1024 + n];
#pragma unroll
        for (int i = 0; i < 16; ++i) acc += bufB[k0 + i] * w[i];
      }
      r0acc[rep] = fmaxf(acc + b3[n], 0.f);
    }
    bufA[tid]       = r0acc[0];
    bufA[tid + 512] = r0acc[1];
  }
  __syncthreads();

  {  // o = u@W4 + b4
    float acc = 0.f;
    for (int k0 = 0; k0 < 1024; k0 += 16) {
      float w[16];
#pragma unroll
      for (int i = 0; i < 16; ++i) w[i] = W4[(size_t)(k0 + i) * 512 + tid];
#pragma unroll
      for (int i = 0; i < 16; ++i) acc += bufA[k0 + i] * w[i];
    }
    bufB[tid] = acc + b4[tid];
  }
  __syncthreads();

  {  // score + softmax
    const int n = tid & 63, q = tid >> 6;
    float p = 0.f;
#pragma unroll
    for (int k0 = 0; k0 < 64; k0 += 16) {
      float w[16];
#pragma unroll
      for (int i = 0; i < 16; ++i) w[i] = Wc[(size_t)(q * 64 + k0 + i) * 64 + n];
#pragma unroll
      for (int i = 0; i < 16; ++i) p += bufB[q * 64 + k0 + i] * w[i];
    }
    scr[tid] = p;
  }
  __syncthreads();
  if (tid < 64) {
    float s = bc[tid];
#pragma unroll
    for (int q = 0; q < 8; ++q) s += scr[q * 64 + tid];
    float m = s;
#pragma unroll
    for (int off = 32; off; off >>= 1) m = fmaxf(m, __shfl_xor(m, off));
    float e = expf(s - m);
    float sum = e;
#pragma unroll
    for (int off = 32; off; off >>= 1) sum += __shfl_xor(sum, off);
    out[(size_t)g * 64 + tid] = e / sum;
  }
}

extern "C" void kernel_launch(void* const* d_in, const int* in_sizes, int n_in,
                              void* d_out, int out_size, void* d_ws, size_t ws_size,
                              hipStream_t stream) {
  const float* x_in = (const float*)d_in[0];
  const int*   tidx = (const int*)d_in[1];
  const float* W1 = (const float*)d_in[2];
  const float* b1 = (const float*)d_in[3];
  const float* W2 = (const float*)d_in[4];
  const float* b2 = (const float*)d_in[5];
  const float* W3 = (const float*)d_in[6];
  const float* b3 = (const float*)d_in[7];
  const float* W4 = (const float*)d_in[8];
  const float* b4 = (const float*)d_in[9];
  const float* Wc = (const float*)d_in[10];
  const float* bc = (const float*)d_in[11];
  float* out = (float*)d_out;
  (void)in_sizes; (void)n_in; (void)out_size; (void)ws_size;

  char* ws = (char*)d_ws;
  __hip_bfloat16* xbf = (__hip_bfloat16*)(ws + 0);        // 2,621,440 B
  __hip_bfloat16* w1t = (__hip_bfloat16*)(ws + 2621440);  // 3,145,728 B
  float* Hs = (float*)(ws + 5767168);                     // 655,360 B

  cast_x<<<5120, 256, 0, stream>>>(x_in, xbf);
  transpose_w1<<<dim3(32, 48), 256, 0, stream>>>(W1, w1t);

  // Hsum via P-decomposition: 8 GFLOP MFMA + LDS gather (was 258 GFLOP)
  group_kernel<<<512, 256, 0, stream>>>(xbf, w1t, tidx, b1, Hs);

  // fused tail: g -> u -> o -> softmax, one block per row
  tail_kernel<<<160, 512, 0, stream>>>(Hs, W2, b2, W3, b3, W4, b4, Wc, bc, out);
}

// Round 4
// 165.919 us; speedup vs baseline: 6.0315x; 1.2548x over previous
//
#include <hip/hip_runtime.h>
#include <hip/hip_bf16.h>

// Problem constants (T,S,W,D,C,K) = (16,16,10,512,64,512)
#define T_  16
#define W_  10
#define D_  512
#define SW_ 160      // S*W
#define N1_ 1024     // 2*D
#define KT_ 512      // triplets per (t,w)

typedef __bf16 bf16x8 __attribute__((ext_vector_type(8)));
typedef float  f32x4  __attribute__((ext_vector_type(4)));

// async global->LDS, 16B per lane (global addr per-lane; LDS dest = wave base + lane*16)
__device__ __forceinline__ void async16(const void* g, void* l) {
  __builtin_amdgcn_global_load_lds(
      (__attribute__((address_space(1))) void*)(g),
      (__attribute__((address_space(3))) void*)(l), 16, 0, 0);
}

__device__ __forceinline__ float lo16(unsigned v) { return __uint_as_float(v << 16); }
__device__ __forceinline__ float hi16(unsigned v) { return __uint_as_float(v & 0xffff0000u); }

// ---------------- K0a: cast input_data fp32 -> bf16 ([16][160][512])
__global__ __launch_bounds__(256) void cast_x(const float* __restrict__ xin,
                                              __hip_bfloat16* __restrict__ xbf) {
  int i = blockIdx.x * 256 + threadIdx.x;   // 5120*256 = 1310720 exact
  xbf[i] = __float2bfloat16(xin[i]);
}

// ---------------- K0b: W1 (1536x1024 fp32 [k][n]) -> w1t (bf16 [n][1536])
__global__ __launch_bounds__(256) void transpose_w1(const float* __restrict__ W1,
                                                    __hip_bfloat16* __restrict__ w1t) {
  __shared__ float tile[32 * 33];
  int k0 = blockIdx.y * 32, n0 = blockIdx.x * 32;
  int c = threadIdx.x & 31, r0 = threadIdx.x >> 5;
#pragma unroll
  for (int i = 0; i < 4; ++i) {
    int r = r0 + i * 8;
    tile[r * 33 + c] = W1[(size_t)(k0 + r) * N1_ + n0 + c];
  }
  __syncthreads();
#pragma unroll
  for (int i = 0; i < 4; ++i) {
    int r = r0 + i * 8;
    w1t[(size_t)(n0 + r) * 1536 + k0 + c] = __float2bfloat16(tile[c * 33 + r]);
  }
}

// ---------------- K0c: batched transpose+cast for tail weights: [R][C] f32 -> [C][R] bf16
__global__ __launch_bounds__(256) void transpose4(
    const float* __restrict__ W2, const float* __restrict__ W3,
    const float* __restrict__ W4, const float* __restrict__ Wc,
    __hip_bfloat16* __restrict__ W2t, __hip_bfloat16* __restrict__ W3t,
    __hip_bfloat16* __restrict__ W4t, __hip_bfloat16* __restrict__ Wct)
{
  const float* src; __hip_bfloat16* dst; int R, C;
  switch (blockIdx.z) {
    case 0:  src = W2; dst = W2t; R = 1024; C = 512;  break;
    case 1:  src = W3; dst = W3t; R = 512;  C = 1024; break;
    case 2:  src = W4; dst = W4t; R = 1024; C = 512;  break;
    default: src = Wc; dst = Wct; R = 512;  C = 64;   break;
  }
  int r0 = blockIdx.y * 32, c0 = blockIdx.x * 32;
  if (r0 >= R || c0 >= C) return;
  __shared__ float tile[32 * 33];
  int c = threadIdx.x & 31, rr = threadIdx.x >> 5;
#pragma unroll
  for (int i = 0; i < 4; ++i) {
    int r = rr + i * 8;
    tile[r * 33 + c] = src[(size_t)(r0 + r) * C + c0 + c];
  }
  __syncthreads();
#pragma unroll
  for (int i = 0; i < 4; ++i) {
    int r = rr + i * 8;
    dst[(size_t)(c0 + r) * R + r0 + c] = __float2bfloat16(tile[c * 33 + r]);
  }
}

// ---------------- K1: fused P-tile GEMM + gather/relu/reduce (outputs bf16 Hs).
__global__ __launch_bounds__(256) void group_kernel(
    const __hip_bfloat16* __restrict__ xbf,   // [16][160][512]
    const __hip_bfloat16* __restrict__ w1t,   // [1024][1536]
    const int* __restrict__ tidx,             // [16][10][3][512]
    const float* __restrict__ b1,             // [1024]
    __hip_bfloat16* __restrict__ Hsb)         // [160][1024] bf16
{
  __shared__ __align__(16) char smem[43008];
  char* Abuf  = smem;                      // [0, 20480)   phase 1
  char* Bbuf  = smem + 20480;              // [20480, 32768) phase 1
  char* Ptile = smem;                      // [0, 34560)   phase 2 (overlaps staging)
  int*  idx_s = (int*)(smem + 34560);      // 1536 ints = 6144 B
  float* red  = (float*)(smem + 40704);    // 4 waves x 32 cols = 512 B

  const int tid = threadIdx.x;
  const int bx  = blockIdx.x;
  const int t   = bx >> 5;
  const int nt  = bx & 31;
  const int n0  = nt << 5;                 // 32-col output window

  const int ln = tid & 63, wv = tid >> 6;
  const int wr = wv >> 1, wc = wv & 1;     // 2x2 wave grid: 80 rows x 48 cols each
  const int col16 = ln & 15, quad = ln >> 4;

  const __hip_bfloat16* xt = xbf + (size_t)t * (SW_ * D_);

  // staging offsets (elements) — swizzle: chunk q stored at q^(r&7)
  int aoff[5], lofA[5];
#pragma unroll
  for (int s = 0; s < 5; ++s) {            // A: 160 rows x 8 chunks = 1280
    int i = s * 256 + tid, r = i >> 3, q = i & 7;
    aoff[s] = r * 512 + ((q ^ (r & 7)) << 3);
    lofA[s] = i << 4;
  }
  int boff[3], lofB[3];
#pragma unroll
  for (int s = 0; s < 3; ++s) {            // B: 96 rows (j*32+nc) x 8 chunks = 768
    int i = s * 256 + tid, r = i >> 3, q = i & 7;
    int nc = r & 31, j = r >> 5;
    boff[s] = (n0 + nc) * 1536 + j * 512 + ((q ^ (r & 7)) << 3);
    lofB[s] = i << 4;
  }

  f32x4 acc[5][3];
#pragma unroll
  for (int a = 0; a < 5; ++a)
#pragma unroll
    for (int b = 0; b < 3; ++b)
      acc[a][b] = (f32x4){0.f, 0.f, 0.f, 0.f};

  // ---- phase 1: K-loop
#pragma unroll 1
  for (int kk = 0; kk < 512; kk += 64) {
    __syncthreads();
#pragma unroll
    for (int s = 0; s < 5; ++s) async16(xt + aoff[s] + kk, Abuf + lofA[s]);
#pragma unroll
    for (int s = 0; s < 3; ++s) async16(w1t + boff[s] + kk, Bbuf + lofB[s]);
    __syncthreads();

#pragma unroll
    for (int ks = 0; ks < 2; ++ks) {
      const int qq = (ks << 2) + quad;
      bf16x8 af[5], bfr[3];
#pragma unroll
      for (int a = 0; a < 5; ++a) {
        int rm = wr * 80 + a * 16 + col16;
        af[a] = *(const bf16x8*)(Abuf + rm * 128 + ((qq ^ (rm & 7)) << 4));
      }
#pragma unroll
      for (int b = 0; b < 3; ++b) {
        int rn = wc * 48 + b * 16 + col16;
        bfr[b] = *(const bf16x8*)(Bbuf + rn * 128 + ((qq ^ (rn & 7)) << 4));
      }
#pragma unroll
      for (int a = 0; a < 5; ++a)
#pragma unroll
        for (int b = 0; b < 3; ++b)
          acc[a][b] = __builtin_amdgcn_mfma_f32_16x16x32_bf16(af[a], bfr[b], acc[a][b], 0, 0, 0);
    }
  }

  __syncthreads();   // all staging reads done; smem now becomes Ptile

  // ---- write P to LDS as bf16, layout [j][sw][nc], row stride 72 B
#pragma unroll
  for (int a = 0; a < 5; ++a)
#pragma unroll
    for (int b = 0; b < 3; ++b) {
      int c = wc * 48 + b * 16 + col16;     // 0..95
      int j = c >> 5, nc = c & 31;
      int mb = wr * 80 + a * 16 + quad * 4;
#pragma unroll
      for (int r = 0; r < 4; ++r)
        *(__hip_bfloat16*)(Ptile + (j * 160 + mb + r) * 72 + nc * 2) =
            __float2bfloat16(acc[a][b][r]);
    }

  // ---- phase 2: gather + relu + reduce over k, per w
  const int nq = tid & 7;                   // 4 cols: nc = nq*4..+3
  const int kq = tid >> 3;                  // 0..31, k in [kq*16, kq*16+16)
  const float4 bias4 = *(const float4*)(b1 + n0 + (nq << 2));

#pragma unroll 1
  for (int w = 0; w < 10; ++w) {
    __syncthreads();                        // Ptile writes done / prev-w idx reads done
    {
      const int* src = tidx + (size_t)(t * 10 + w) * 1536;
      async16(src + (tid << 2), (char*)idx_s + (tid << 4));
      if (tid < 128) async16(src + 1024 + (tid << 2), (char*)idx_s + 4096 + (tid << 4));
    }
    __syncthreads();                        // idx ready (barrier drains vmcnt)

    f32x4 a4 = (f32x4){0.f, 0.f, 0.f, 0.f};
#pragma unroll
    for (int u = 0; u < 4; ++u) {
      const int kb = (kq << 4) + (u << 2);
      int4 i0 = *(const int4*)(idx_s + kb);
      int4 i1 = *(const int4*)(idx_s + 512 + kb);
      int4 i2 = *(const int4*)(idx_s + 1024 + kb);
#define STEP(IA, IB, IC)                                                          \
      {                                                                           \
        uint2 p0 = *(const uint2*)(Ptile + (IA) * 72 + (nq << 3));                \
        uint2 p1 = *(const uint2*)(Ptile + 11520 + (IB) * 72 + (nq << 3));        \
        uint2 p2 = *(const uint2*)(Ptile + 23040 + (IC) * 72 + (nq << 3));        \
        a4.x += fmaxf(lo16(p0.x) + lo16(p1.x) + lo16(p2.x) + bias4.x, 0.f);       \
        a4.y += fmaxf(hi16(p0.x) + hi16(p1.x) + hi16(p2.x) + bias4.y, 0.f);       \
        a4.z += fmaxf(lo16(p0.y) + lo16(p1.y) + lo16(p2.y) + bias4.z, 0.f);       \
        a4.w += fmaxf(hi16(p0.y) + hi16(p1.y) + hi16(p2.y) + bias4.w, 0.f);       \
      }
      STEP(i0.x, i1.x, i2.x)
      STEP(i0.y, i1.y, i2.y)
      STEP(i0.z, i1.z, i2.z)
      STEP(i0.w, i1.w, i2.w)
#undef STEP
    }

    // reduce over kq (lane bits 3..5), then across waves via LDS
#pragma unroll
    for (int off = 8; off <= 32; off <<= 1) {
      a4.x += __shfl_xor(a4.x, off);
      a4.y += __shfl_xor(a4.y, off);
      a4.z += __shfl_xor(a4.z, off);
      a4.w += __shfl_xor(a4.w, off);
    }
    if ((ln >> 3) == 0)
      *(f32x4*)(red + wv * 32 + (nq << 2)) = a4;
    __syncthreads();
    if (tid < 32) {
      float s = red[tid] + red[32 + tid] + red[64 + tid] + red[96 + tid];
      Hsb[(size_t)(t * 10 + w) * N1_ + n0 + tid] = __float2bfloat16(s);
    }
  }
}

// ---------------- K2: column-parallel bf16 MFMA tail GEMM.
// out[160][N] = maybe_relu(A[160][K] @ Bt[N][K]^T + bscale*bias), bf16 out.
// Grid (N/64, 2): block does 80 rows x 64 cols; 4 waves = 4 n-tiles; 5 m-tiles/wave.
__global__ __launch_bounds__(256) void tail_gemm(
    const __hip_bfloat16* __restrict__ A,
    const __hip_bfloat16* __restrict__ Bt,
    const float* __restrict__ bias, float bscale, int relu, int K, int N,
    __hip_bfloat16* __restrict__ out)
{
  __shared__ __align__(16) char Abuf[20480];  // 80 rows x 256 B (BK=128)
  __shared__ __align__(16) char Bbuf[16384];  // 64 rows x 256 B
  const int tid = threadIdx.x;
  const int n0 = blockIdx.x << 6;
  const int m0 = blockIdx.y * 80;
  const int ln = tid & 63, wv = tid >> 6;
  const int col16 = ln & 15, quad = ln >> 4;

  f32x4 acc[5];
#pragma unroll
  for (int a = 0; a < 5; ++a) acc[a] = (f32x4){0.f, 0.f, 0.f, 0.f};

#pragma unroll 1
  for (int kk = 0; kk < K; kk += 128) {
    __syncthreads();
#pragma unroll
    for (int p = 0; p < 5; ++p) {           // A: 80 rows x 16 chunks
      int i = p * 256 + tid, r = i >> 4, q = i & 15;
      async16(A + (size_t)(m0 + r) * K + kk + ((q ^ (r & 7)) << 3), Abuf + (i << 4));
    }
#pragma unroll
    for (int p = 0; p < 4; ++p) {           // B: 64 rows x 16 chunks
      int i = p * 256 + tid, r = i >> 4, q = i & 15;
      async16(Bt + (size_t)(n0 + r) * K + kk + ((q ^ (r & 7)) << 3), Bbuf + (i << 4));
    }
    __syncthreads();

#pragma unroll
    for (int ks = 0; ks < 4; ++ks) {
      const int qq = (ks << 2) + quad;
      const int rn = (wv << 4) + col16;
      bf16x8 bf = *(const bf16x8*)(Bbuf + rn * 256 + ((qq ^ (rn & 7)) << 4));
#pragma unroll
      for (int a = 0; a < 5; ++a) {
        int rm = (a << 4) + col16;
        bf16x8 af = *(const bf16x8*)(Abuf + rm * 256 + ((qq ^ (rm & 7)) << 4));
        acc[a] = __builtin_amdgcn_mfma_f32_16x16x32_bf16(af, bf, acc[a], 0, 0, 0);
      }
    }
  }

  const int n = n0 + (wv << 4) + col16;
  const float bb = bias[n] * bscale;
#pragma unroll
  for (int a = 0; a < 5; ++a)
#pragma unroll
    for (int r = 0; r < 4; ++r) {
      float v = acc[a][r] + bb;
      if (relu) v = fmaxf(v, 0.f);
      out[(size_t)(m0 + (a << 4) + (quad << 2) + r) * N + n] = __float2bfloat16(v);
    }
}

// ---------------- K3: head: score = ob@Wct^T + bc, softmax over 64. Grid (2): 80 rows/block.
__global__ __launch_bounds__(256) void head_gemm(
    const __hip_bfloat16* __restrict__ A,    // ob [160][512]
    const __hip_bfloat16* __restrict__ Bt,   // Wct [64][512]
    const float* __restrict__ bc,
    float* __restrict__ out)                 // [160][64]
{
  __shared__ __align__(16) char Abuf[20480];
  __shared__ __align__(16) char Bbuf[16384];
  __shared__ float sc[80 * 64];
  __shared__ float rs[80];
  const int tid = threadIdx.x;
  const int m0 = blockIdx.x * 80;
  const int ln = tid & 63, wv = tid >> 6;
  const int col16 = ln & 15, quad = ln >> 4;

  f32x4 acc[5];
#pragma unroll
  for (int a = 0; a < 5; ++a) acc[a] = (f32x4){0.f, 0.f, 0.f, 0.f};

#pragma unroll 1
  for (int kk = 0; kk < 512; kk += 128) {
    __syncthreads();
#pragma unroll
    for (int p = 0; p < 5; ++p) {
      int i = p * 256 + tid, r = i >> 4, q = i & 15;
      async16(A + (size_t)(m0 + r) * 512 + kk + ((q ^ (r & 7)) << 3), Abuf + (i << 4));
    }
#pragma unroll
    for (int p = 0; p < 4; ++p) {
      int i = p * 256 + tid, r = i >> 4, q = i & 15;
      async16(Bt + (size_t)r * 512 + kk + ((q ^ (r & 7)) << 3), Bbuf + (i << 4));
    }
    __syncthreads();

#pragma unroll
    for (int ks = 0; ks < 4; ++ks) {
      const int qq = (ks << 2) + quad;
      const int rn = (wv << 4) + col16;
      bf16x8 bf = *(const bf16x8*)(Bbuf + rn * 256 + ((qq ^ (rn & 7)) << 4));
#pragma unroll
      for (int a = 0; a < 5; ++a) {
        int rm = (a << 4) + col16;
        bf16x8 af = *(const bf16x8*)(Abuf + rm * 256 + ((qq ^ (rm & 7)) << 4));
        acc[a] = __builtin_amdgcn_mfma_f32_16x16x32_bf16(af, bf, acc[a], 0, 0, 0);
      }
    }
  }

  const int n = (wv << 4) + col16;
  const float bb = bc[n];
#pragma unroll
  for (int a = 0; a < 5; ++a)
#pragma unroll
    for (int r = 0; r < 4; ++r)
      sc[((a << 4) + (quad << 2) + r) * 64 + n] = acc[a][r] + bb;
  __syncthreads();

  if (tid < 80) {
    float m = -1e30f;
    for (int c = 0; c < 64; ++c) m = fmaxf(m, sc[tid * 64 + c]);
    float s = 0.f;
    for (int c = 0; c < 64; ++c) {
      float e = expf(sc[tid * 64 + c] - m);
      sc[tid * 64 + c] = e;
      s += e;
    }
    rs[tid] = 1.f / s;
  }
  __syncthreads();
#pragma unroll
  for (int p = 0; p < 20; ++p) {
    int f = p * 256 + tid, r = f >> 6, c = f & 63;
    out[(size_t)(m0 + r) * 64 + c] = sc[f] * rs[r];
  }
}

extern "C" void kernel_launch(void* const* d_in, const int* in_sizes, int n_in,
                              void* d_out, int out_size, void* d_ws, size_t ws_size,
                              hipStream_t stream) {
  const float* x_in = (const float*)d_in[0];
  const int*   tidx = (const int*)d_in[1];
  const float* W1 = (const float*)d_in[2];
  const float* b1 = (const float*)d_in[3];
  const float* W2 = (const float*)d_in[4];
  const float* b2 = (const float*)d_in[5];
  const float* W3 = (const float*)d_in[6];
  const float* b3 = (const float*)d_in[7];
  const float* W4 = (const float*)d_in[8];
  const float* b4 = (const float*)d_in[9];
  const float* Wc = (const float*)d_in[10];
  const float* bc = (const float*)d_in[11];
  float* out = (float*)d_out;
  (void)in_sizes; (void)n_in; (void)out_size; (void)ws_size;

  char* ws = (char*)d_ws;
  // Region A [0, 5767168): xbf+w1t during group_kernel; reused for tail weights after.
  __hip_bfloat16* xbf = (__hip_bfloat16*)(ws + 0);        // 2,621,440 B
  __hip_bfloat16* w1t = (__hip_bfloat16*)(ws + 2621440);  // 3,145,728 B -> 5,767,168
  __hip_bfloat16* W2t = (__hip_bfloat16*)(ws + 0);        // [512][1024] bf16 = 1 MiB
  __hip_bfloat16* W3t = (__hip_bfloat16*)(ws + 1048576);  // [1024][512]
  __hip_bfloat16* W4t = (__hip_bfloat16*)(ws + 2097152);  // [512][1024]
  __hip_bfloat16* Wct = (__hip_bfloat16*)(ws + 3145728);  // [64][512] = 64 KiB
  __hip_bfloat16* Hsb = (__hip_bfloat16*)(ws + 5767168);  // [160][1024] = 320 KiB
  __hip_bfloat16* gb  = (__hip_bfloat16*)(ws + 6094848);  // [160][512]  = 160 KiB
  __hip_bfloat16* ub  = (__hip_bfloat16*)(ws + 6258688);  // [160][1024] = 320 KiB
  __hip_bfloat16* ob  = (__hip_bfloat16*)(ws + 6586368);  // [160][512]  = 160 KiB

  cast_x<<<5120, 256, 0, stream>>>(x_in, xbf);
  transpose_w1<<<dim3(32, 48), 256, 0, stream>>>(W1, w1t);

  // Hsum (bf16) via P-decomposition: 8 GFLOP MFMA + LDS gather
  group_kernel<<<512, 256, 0, stream>>>(xbf, w1t, tidx, b1, Hsb);

  // tail weight transposes (reuse xbf/w1t region — group_kernel is done with it)
  transpose4<<<dim3(32, 32, 4), 256, 0, stream>>>(W2, W3, W4, Wc, W2t, W3t, W4t, Wct);

  // g = Hs@W2 + 512*b2
  tail_gemm<<<dim3(8, 2), 256, 0, stream>>>(Hsb, W2t, b2, (float)KT_, 0, 1024, 512, gb);
  // u = relu(g@W3 + b3)
  tail_gemm<<<dim3(16, 2), 256, 0, stream>>>(gb, W3t, b3, 1.f, 1, 512, 1024, ub);
  // o = u@W4 + b4
  tail_gemm<<<dim3(8, 2), 256, 0, stream>>>(ub, W4t, b4, 1.f, 0, 1024, 512, ob);
  // softmax(o@Wc + bc)
  head_gemm<<<2, 256, 0, stream>>>(ob, Wct, bc, out);
}